// Round 10
// baseline (95.140 us; speedup 1.0000x reference)
//
#include <hip/hip_runtime.h>
#include <math.h>

#define NTOK 16384   // B*S
#define DDIM 2048
#define NEXP 64
#define NKQ 8        // K split into 8 slices
#define KSLICE 256   // k per slice (8 ksteps of 32)
#define TPB 128      // tokens per gemm block (8 waves x 16)

typedef __attribute__((ext_vector_type(8))) short bf16x8;
typedef __attribute__((ext_vector_type(4))) float f32x4;

// ws layout (bytes):
//   [0, 516)        aux accumulators (zeroed per call)
//   [1024, 787456)  wp: packed W fragments, ks-major: [64 ks][4 eg][3 part][512 shorts]
//   [1MB, 33MB)     partial logits [8 kq][16384 tok][64 exp] fp32

// ---- packed 3-way bf16 split of a float pair via v_cvt_pk_bf16_f32 ----
// H/M/L each hold {bf16(lo) in bits 0-15, bf16(hi) in bits 16-31} — exactly
// the MFMA operand layout for two consecutive k. Residuals are exact fp32
// subtractions, so the 6-pass reconstruction error stays ~2^-27 regardless
// of the HW convert's tie behavior.
__device__ __forceinline__ void split3pk(float a, float b,
                                         unsigned &H, unsigned &M, unsigned &L) {
    asm("v_cvt_pk_bf16_f32 %0, %1, %2" : "=v"(H) : "v"(a), "v"(b));
    float ra = a - __builtin_bit_cast(float, H << 16);
    float rb = b - __builtin_bit_cast(float, H & 0xffff0000u);
    asm("v_cvt_pk_bf16_f32 %0, %1, %2" : "=v"(M) : "v"(ra), "v"(rb));
    float sa = ra - __builtin_bit_cast(float, M << 16);
    float sb = rb - __builtin_bit_cast(float, M & 0xffff0000u);
    asm("v_cvt_pk_bf16_f32 %0, %1, %2" : "=v"(L) : "v"(sa), "v"(sb));
}

// ---- pack gate_w into ks-major B-fragment layout ----
// wp[ks][eg][part][lane*8 shorts]; B-frag: col(expert)=lane&15, k=(lane>>4)*8+j
__global__ void k_wpack(const float* __restrict__ gw, unsigned short* __restrict__ wp) {
    int idx = blockIdx.x * 256 + threadIdx.x;   // 16384 threads
    int lane = idx & 63;
    int ks   = (idx >> 6) & 63;                 // global k-step (32 k each)
    int eg   = idx >> 12;                       // expert group 0..3
    int e  = eg * 16 + (lane & 15);
    int k0 = ks * 32 + (lane >> 4) * 8;
    const float* src = gw + (size_t)e * DDIM + k0;
    uint4 H, M, L;
    split3pk(src[0], src[1], H.x, M.x, L.x);
    split3pk(src[2], src[3], H.y, M.y, L.y);
    split3pk(src[4], src[5], H.z, M.z, L.z);
    split3pk(src[6], src[7], H.w, M.w, L.w);
    size_t fb = ((size_t)ks * 12 + eg * 3) * 512 + lane * 8;   // shorts
    *(uint4*)(wp + fb)        = H;
    *(uint4*)(wp + fb + 512)  = M;
    *(uint4*)(wp + fb + 1024) = L;
}

// ---- phase 1: K-sliced GEMM; W reg-staged (T14) into LDS halves; x->regs ----
// launch_bounds (512, 2): register budget 128 — the ~96 live VGPRs (wreg[6],
// xf[4][2], A-frags, acc) MUST fit without scratch spill. Round-9's (512,4)
// capped the budget at 64 and spilled the staging arrays into the inner loop
// (VGPR_Count=40, +48MB scratch writes) — that spill was the serializer.
__global__ __launch_bounds__(512, 2)
void k_gemm(const float* __restrict__ x, const unsigned short* __restrict__ wp,
            float* __restrict__ part) {
    // Ws: [4 ks][4 eg][3 part][1024 B] = one half (48 KB), layout = wp slice
    __shared__ __align__(16) char Ws[49152];

    const int tid  = threadIdx.x;
    const int kq   = blockIdx.x & 7;
    const int tok0 = (blockIdx.x >> 3) * TPB;
    const int lane = tid & 63;
    const int wv   = tid >> 6;
    const int tau  = lane & 15;
    const int kap  = lane >> 4;

    // ---- x prefetch ring (4 ksteps)
    const float* xb = x + (size_t)(tok0 + wv * 16 + tau) * DDIM
                        + kq * KSLICE + kap * 8;
    float4 xf[4][2];
    #pragma unroll
    for (int i = 0; i < 4; ++i) {
        xf[i][0] = *(const float4*)(xb + i * 32);
        xf[i][1] = *(const float4*)(xb + i * 32 + 4);
    }

    // ---- T14: preload W half 0 into registers (6 uint4/thread = whole 48 KB)
    const char* wsrc = (const char*)wp + (size_t)(kq * 8) * 12288;
    uint4 wreg[6];
    #pragma unroll
    for (int r = 0; r < 6; ++r)
        wreg[r] = *(const uint4*)(wsrc + (r * 512 + tid) * 16);

    f32x4 acc[4];
    #pragma unroll
    for (int eg = 0; eg < 4; ++eg) acc[eg] = (f32x4){0.f, 0.f, 0.f, 0.f};

    for (int h = 0; h < 2; ++h) {
        if (h) __syncthreads();   // all reads of previous half complete
        // ---- write staged regs to LDS
        #pragma unroll
        for (int r = 0; r < 6; ++r)
            *(uint4*)(Ws + (r * 512 + tid) * 16) = wreg[r];
        // ---- issue half-1 global loads NOW (complete under half-0 compute)
        if (h == 0) {
            #pragma unroll
            for (int r = 0; r < 6; ++r)
                wreg[r] = *(const uint4*)(wsrc + 49152 + (r * 512 + tid) * 16);
        }
        __syncthreads();

        // ---- 4 MFMA k-steps on this half
        #pragma unroll
        for (int ks = 0; ks < 4; ++ks) {
            float4 a = xf[ks][0], b = xf[ks][1];
            uint4 Ah, Am, Al;
            split3pk(a.x, a.y, Ah.x, Am.x, Al.x);
            split3pk(a.z, a.w, Ah.y, Am.y, Al.y);
            split3pk(b.x, b.y, Ah.z, Am.z, Al.z);
            split3pk(b.z, b.w, Ah.w, Am.w, Al.w);
            bf16x8 Ahv = __builtin_bit_cast(bf16x8, Ah);
            bf16x8 Amv = __builtin_bit_cast(bf16x8, Am);
            bf16x8 Alv = __builtin_bit_cast(bf16x8, Al);

            if (h == 0) {   // refill ring for half 1
                xf[ks][0] = *(const float4*)(xb + 128 + ks * 32);
                xf[ks][1] = *(const float4*)(xb + 128 + ks * 32 + 4);
            }

            #pragma unroll
            for (int eg = 0; eg < 4; ++eg) {
                const char* wb = Ws + ks * 12288 + eg * 3072 + lane * 16;
                bf16x8 Bh = *(const bf16x8*)(wb);
                bf16x8 Bm = *(const bf16x8*)(wb + 1024);
                bf16x8 Bl = *(const bf16x8*)(wb + 2048);
                acc[eg] = __builtin_amdgcn_mfma_f32_16x16x32_bf16(Ahv, Bh, acc[eg], 0, 0, 0);
                acc[eg] = __builtin_amdgcn_mfma_f32_16x16x32_bf16(Ahv, Bm, acc[eg], 0, 0, 0);
                acc[eg] = __builtin_amdgcn_mfma_f32_16x16x32_bf16(Amv, Bh, acc[eg], 0, 0, 0);
                acc[eg] = __builtin_amdgcn_mfma_f32_16x16x32_bf16(Ahv, Bl, acc[eg], 0, 0, 0);
                acc[eg] = __builtin_amdgcn_mfma_f32_16x16x32_bf16(Alv, Bh, acc[eg], 0, 0, 0);
                acc[eg] = __builtin_amdgcn_mfma_f32_16x16x32_bf16(Amv, Bm, acc[eg], 0, 0, 0);
            }
        }
    }

    // ---- store partials: part[kq][tok][e]; C/D: col=tau(exp), row=kap*4+j(tok)
    float* pb = part + ((size_t)kq * NTOK + tok0 + wv * 16) * 64;
    #pragma unroll
    for (int eg = 0; eg < 4; ++eg)
        #pragma unroll
        for (int j = 0; j < 4; ++j)
            pb[(kap * 4 + j) * 64 + eg * 16 + tau] = acc[eg][j];
}

// ---- phase 2: deterministic K-reduction + softmax / top-2 / aux (validated) --
__global__ __launch_bounds__(256)
void k_reduce(const float* __restrict__ part, float* __restrict__ out,
              float* __restrict__ gcnt, float* __restrict__ gP,
              float* __restrict__ gz) {
    __shared__ float Ps[NEXP], Cnt[NEXP], Zs;
    const int tid = threadIdx.x;
    if (tid < NEXP) { Ps[tid] = 0.f; Cnt[tid] = 0.f; }
    if (tid == 0) Zs = 0.f;
    __syncthreads();

    const int lane = tid & 63;
    const int wv   = tid >> 6;
    const int t0   = blockIdx.x * 16 + wv * 4;

    float v[4][8];
    #pragma unroll
    for (int i = 0; i < 4; ++i)
        #pragma unroll
        for (int q = 0; q < 8; ++q)
            v[i][q] = part[((size_t)q * NTOK + t0 + i) * 64 + lane];

    float Pacc = 0.f, zacc = 0.f;
    #pragma unroll
    for (int i = 0; i < 4; ++i) {
        float l = ((v[i][0] + v[i][1]) + (v[i][2] + v[i][3]))
                + ((v[i][4] + v[i][5]) + (v[i][6] + v[i][7]));
        float mx = l;
        #pragma unroll
        for (int off = 32; off > 0; off >>= 1) mx = fmaxf(mx, __shfl_xor(mx, off));
        float s = expf(l - mx);
        float sum = s;
        #pragma unroll
        for (int off = 32; off > 0; off >>= 1) sum += __shfl_xor(sum, off);
        Pacc += s / sum;

        unsigned long long b1 = __ballot(l == mx);
        int i1 = __ffsll(b1) - 1;              // lowest index on ties
        float l2 = (lane == i1) ? -INFINITY : l;
        float m2 = l2;
        #pragma unroll
        for (int off = 32; off > 0; off >>= 1) m2 = fmaxf(m2, __shfl_xor(m2, off));
        unsigned long long b2 = __ballot(l2 == m2);
        int i2 = __ffsll(b2) - 1;

        if (lane == 0) {
            float s2  = expf(m2 - mx);
            float inv = 1.f / (1.f + s2);
            int gt = t0 + i;
            ((float2*)out)[gt]              = make_float2((float)i1, (float)i2);
            ((float2*)(out + 2 * NTOK))[gt] = make_float2(inv, s2 * inv);
            atomicAdd(&Cnt[i1], 1.f);
            atomicAdd(&Cnt[i2], 1.f);
            float lse = mx + logf(sum);
            zacc += lse * lse;
        }
    }
    atomicAdd(&Ps[lane], Pacc);
    if (lane == 0) atomicAdd(&Zs, zacc);
    __syncthreads();

    if (tid < NEXP) {
        atomicAdd(&gcnt[tid], Cnt[tid]);
        atomicAdd(&gP[tid],   Ps[tid]);
    }
    if (tid == 0) atomicAdd(gz, Zs);
}

__global__ void k_final(const float* __restrict__ ws, float* __restrict__ out) {
    int lane = threadIdx.x;
    float v = ws[lane] * ws[64 + lane];
    #pragma unroll
    for (int off = 32; off > 0; off >>= 1) v += __shfl_xor(v, off);
    if (lane == 0) {
        float bal = 64.f * v / (32768.f * 16384.f);
        float z   = ws[128] / 16384.f;
        out[4 * NTOK] = 0.01f * bal + 0.001f * z;
    }
}

extern "C" void kernel_launch(void* const* d_in, const int* in_sizes, int n_in,
                              void* d_out, int out_size, void* d_ws, size_t ws_size,
                              hipStream_t stream) {
    const float* x  = (const float*)d_in[0];
    const float* gw = (const float*)d_in[1];
    float* out = (float*)d_out;
    float* wsf = (float*)d_ws;
    unsigned short* wp = (unsigned short*)((char*)d_ws + 1024);
    float* part = (float*)((char*)d_ws + (1 << 20));

    hipMemsetAsync(d_ws, 0, 516, stream);
    k_wpack<<<64, 256, 0, stream>>>(gw, wp);
    k_gemm<<<NKQ * (NTOK / TPB), 512, 0, stream>>>(x, wp, part);
    k_reduce<<<NTOK / 16, 256, 0, stream>>>(part, out, wsf, wsf + 64, wsf + 128);
    k_final<<<1, 64, 0, stream>>>(wsf, out);
}

// Round 11
// 83.630 us; speedup vs baseline: 1.1376x; 1.1376x over previous
//
#include <hip/hip_runtime.h>
#include <math.h>

#define NTOK 16384   // B*S
#define DDIM 2048
#define NEXP 64
#define NKQ 16       // K split into 16 slices
#define KSLICE 128   // k per slice (4 ksteps of 32)
#define TPB 64       // tokens per gemm block (4 waves x 16)

typedef __attribute__((ext_vector_type(8))) short bf16x8;
typedef __attribute__((ext_vector_type(4))) float f32x4;

// ws layout (bytes):
//   [0, 516)        aux accumulators (zeroed per call)
//   [1024, 787456)  wp: packed W fragments, ks-major: [64 ks][4 eg][3 part][512 shorts]
//   [1MB, 65MB)     partial logits [16 kq][16384 tok][64 exp] fp32

// ---- packed 3-way bf16 split of a float pair via v_cvt_pk_bf16_f32 ----
__device__ __forceinline__ void split3pk(float a, float b,
                                         unsigned &H, unsigned &M, unsigned &L) {
    asm("v_cvt_pk_bf16_f32 %0, %1, %2" : "=v"(H) : "v"(a), "v"(b));
    float ra = a - __builtin_bit_cast(float, H << 16);
    float rb = b - __builtin_bit_cast(float, H & 0xffff0000u);
    asm("v_cvt_pk_bf16_f32 %0, %1, %2" : "=v"(M) : "v"(ra), "v"(rb));
    float sa = ra - __builtin_bit_cast(float, M << 16);
    float sb = rb - __builtin_bit_cast(float, M & 0xffff0000u);
    asm("v_cvt_pk_bf16_f32 %0, %1, %2" : "=v"(L) : "v"(sa), "v"(sb));
}

__device__ __forceinline__ void keepf(float4 &v) {
    asm volatile("" : "+v"(v.x), "+v"(v.y), "+v"(v.z), "+v"(v.w));
}

// ---- pack gate_w into ks-major B-fragment layout (validated) ----
__global__ void k_wpack(const float* __restrict__ gw, unsigned short* __restrict__ wp) {
    int idx = blockIdx.x * 256 + threadIdx.x;   // 16384 threads
    int lane = idx & 63;
    int ks   = (idx >> 6) & 63;                 // global k-step (32 k each)
    int eg   = idx >> 12;                       // expert group 0..3
    int e  = eg * 16 + (lane & 15);
    int k0 = ks * 32 + (lane >> 4) * 8;
    const float* src = gw + (size_t)e * DDIM + k0;
    uint4 H, M, L;
    split3pk(src[0], src[1], H.x, M.x, L.x);
    split3pk(src[2], src[3], H.y, M.y, L.y);
    split3pk(src[4], src[5], H.z, M.z, L.z);
    split3pk(src[6], src[7], H.w, M.w, L.w);
    size_t fb = ((size_t)ks * 12 + eg * 3) * 512 + lane * 8;   // shorts
    *(uint4*)(wp + fb)        = H;
    *(uint4*)(wp + fb + 512)  = M;
    *(uint4*)(wp + fb + 1024) = L;
}

// ---- phase 1: K-sliced GEMM. W via global_load_lds (zero staging regs),
// x fully preloaded to named registers, ONE barrier, then pure compute. ----
__global__ __launch_bounds__(256, 2)
void k_gemm(const float* __restrict__ x, const unsigned short* __restrict__ wp,
            float* __restrict__ part) {
    // Ws: [4 ks][4 eg][3 part][1024 B] = this block's whole W slice (48 KB)
    __shared__ __align__(16) char Ws[49152];

    const int tid  = threadIdx.x;
    const int kq   = blockIdx.x & 15;            // k slice
    const int tok0 = (blockIdx.x >> 4) * TPB;    // token chunk base
    const int lane = tid & 63;
    const int wvu  = __builtin_amdgcn_readfirstlane(tid >> 6);  // wave 0..3
    const int tau  = lane & 15;
    const int kap  = lane >> 4;

    // ---- async-stage the whole W slice into LDS (12 x 4KB, linear) ----
    {
        const char* wsrc = (const char*)wp + (size_t)kq * 49152;
        #pragma unroll
        for (int r = 0; r < 12; ++r) {
            const char* g = wsrc + (size_t)(r * 256 + tid) * 16;
            char* l = Ws + (size_t)(r * 256 + wvu * 64) * 16;   // wave-uniform base
            __builtin_amdgcn_global_load_lds(
                (const __attribute__((address_space(1))) void*)g,
                (__attribute__((address_space(3))) void*)l, 16, 0, 0);
        }
    }

    // ---- preload this thread's entire x slice (8 named float4 = 32 VGPR)
    const float* xb = x + (size_t)(tok0 + wvu * 16 + tau) * DDIM
                        + kq * KSLICE + kap * 8;
    float4 x0a = *(const float4*)(xb);
    float4 x0b = *(const float4*)(xb + 4);
    float4 x1a = *(const float4*)(xb + 32);
    float4 x1b = *(const float4*)(xb + 36);
    float4 x2a = *(const float4*)(xb + 64);
    float4 x2b = *(const float4*)(xb + 68);
    float4 x3a = *(const float4*)(xb + 96);
    float4 x3b = *(const float4*)(xb + 100);
    keepf(x0a); keepf(x0b); keepf(x1a); keepf(x1b);
    keepf(x2a); keepf(x2b); keepf(x3a); keepf(x3b);

    __syncthreads();   // vmcnt(0) drains gload_lds + x loads; LDS ready

    f32x4 acc[4];
    #pragma unroll
    for (int eg = 0; eg < 4; ++eg) acc[eg] = (f32x4){0.f, 0.f, 0.f, 0.f};

    // ---- 4 MFMA k-steps, zero global-memory dependencies ----
    #pragma unroll
    for (int ks = 0; ks < 4; ++ks) {
        float4 a = (ks == 0) ? x0a : (ks == 1) ? x1a : (ks == 2) ? x2a : x3a;
        float4 b = (ks == 0) ? x0b : (ks == 1) ? x1b : (ks == 2) ? x2b : x3b;
        uint4 Ah, Am, Al;
        split3pk(a.x, a.y, Ah.x, Am.x, Al.x);
        split3pk(a.z, a.w, Ah.y, Am.y, Al.y);
        split3pk(b.x, b.y, Ah.z, Am.z, Al.z);
        split3pk(b.z, b.w, Ah.w, Am.w, Al.w);
        bf16x8 Ahv = __builtin_bit_cast(bf16x8, Ah);
        bf16x8 Amv = __builtin_bit_cast(bf16x8, Am);
        bf16x8 Alv = __builtin_bit_cast(bf16x8, Al);

        #pragma unroll
        for (int eg = 0; eg < 4; ++eg) {
            const char* wb = Ws + ks * 12288 + eg * 3072 + lane * 16;
            bf16x8 Bh = *(const bf16x8*)(wb);
            bf16x8 Bm = *(const bf16x8*)(wb + 1024);
            bf16x8 Bl = *(const bf16x8*)(wb + 2048);
            acc[eg] = __builtin_amdgcn_mfma_f32_16x16x32_bf16(Ahv, Bh, acc[eg], 0, 0, 0);
            acc[eg] = __builtin_amdgcn_mfma_f32_16x16x32_bf16(Ahv, Bm, acc[eg], 0, 0, 0);
            acc[eg] = __builtin_amdgcn_mfma_f32_16x16x32_bf16(Amv, Bh, acc[eg], 0, 0, 0);
            acc[eg] = __builtin_amdgcn_mfma_f32_16x16x32_bf16(Ahv, Bl, acc[eg], 0, 0, 0);
            acc[eg] = __builtin_amdgcn_mfma_f32_16x16x32_bf16(Alv, Bh, acc[eg], 0, 0, 0);
            acc[eg] = __builtin_amdgcn_mfma_f32_16x16x32_bf16(Amv, Bm, acc[eg], 0, 0, 0);
        }
    }

    // ---- store partials: part[kq][tok][e]; C/D: col=tau(exp), row=kap*4+j(tok)
    float* pb = part + ((size_t)kq * NTOK + tok0 + wvu * 16) * 64;
    #pragma unroll
    for (int eg = 0; eg < 4; ++eg)
        #pragma unroll
        for (int j = 0; j < 4; ++j)
            pb[(kap * 4 + j) * 64 + eg * 16 + tau] = acc[eg][j];
}

// ---- phase 2: deterministic 16-slice K-reduction + softmax/top-2/aux ----
__global__ __launch_bounds__(256, 2)
void k_reduce(const float* __restrict__ part, float* __restrict__ out,
              float* __restrict__ gcnt, float* __restrict__ gP,
              float* __restrict__ gz) {
    __shared__ float Ps[NEXP], Cnt[NEXP], Zs;
    const int tid = threadIdx.x;
    if (tid < NEXP) { Ps[tid] = 0.f; Cnt[tid] = 0.f; }
    if (tid == 0) Zs = 0.f;
    __syncthreads();

    const int lane = tid & 63;
    const int wv   = tid >> 6;
    const int t0   = blockIdx.x * 16 + wv * 4;   // 4 tokens per wave

    // fixed-order sum over the 16 k-slices (deterministic)
    float l4[4] = {0.f, 0.f, 0.f, 0.f};
    #pragma unroll
    for (int q = 0; q < NKQ; ++q)
        #pragma unroll
        for (int i = 0; i < 4; ++i)
            l4[i] += part[((size_t)q * NTOK + t0 + i) * 64 + lane];

    float Pacc = 0.f, zacc = 0.f;
    #pragma unroll
    for (int i = 0; i < 4; ++i) {
        float l = l4[i];
        float mx = l;
        #pragma unroll
        for (int off = 32; off > 0; off >>= 1) mx = fmaxf(mx, __shfl_xor(mx, off));
        float s = expf(l - mx);
        float sum = s;
        #pragma unroll
        for (int off = 32; off > 0; off >>= 1) sum += __shfl_xor(sum, off);
        Pacc += s / sum;

        unsigned long long b1 = __ballot(l == mx);
        int i1 = __ffsll(b1) - 1;              // lowest index on ties
        float l2 = (lane == i1) ? -INFINITY : l;
        float m2 = l2;
        #pragma unroll
        for (int off = 32; off > 0; off >>= 1) m2 = fmaxf(m2, __shfl_xor(m2, off));
        unsigned long long b2 = __ballot(l2 == m2);
        int i2 = __ffsll(b2) - 1;

        if (lane == 0) {
            float s2  = expf(m2 - mx);
            float inv = 1.f / (1.f + s2);
            int gt = t0 + i;
            ((float2*)out)[gt]              = make_float2((float)i1, (float)i2);
            ((float2*)(out + 2 * NTOK))[gt] = make_float2(inv, s2 * inv);
            atomicAdd(&Cnt[i1], 1.f);
            atomicAdd(&Cnt[i2], 1.f);
            float lse = mx + logf(sum);
            zacc += lse * lse;
        }
    }
    atomicAdd(&Ps[lane], Pacc);
    if (lane == 0) atomicAdd(&Zs, zacc);
    __syncthreads();

    if (tid < NEXP) {
        atomicAdd(&gcnt[tid], Cnt[tid]);
        atomicAdd(&gP[tid],   Ps[tid]);
    }
    if (tid == 0) atomicAdd(gz, Zs);
}

__global__ void k_final(const float* __restrict__ ws, float* __restrict__ out) {
    int lane = threadIdx.x;
    float v = ws[lane] * ws[64 + lane];
    #pragma unroll
    for (int off = 32; off > 0; off >>= 1) v += __shfl_xor(v, off);
    if (lane == 0) {
        float bal = 64.f * v / (32768.f * 16384.f);
        float z   = ws[128] / 16384.f;
        out[4 * NTOK] = 0.01f * bal + 0.001f * z;
    }
}

extern "C" void kernel_launch(void* const* d_in, const int* in_sizes, int n_in,
                              void* d_out, int out_size, void* d_ws, size_t ws_size,
                              hipStream_t stream) {
    const float* x  = (const float*)d_in[0];
    const float* gw = (const float*)d_in[1];
    float* out = (float*)d_out;
    float* wsf = (float*)d_ws;
    unsigned short* wp = (unsigned short*)((char*)d_ws + 1024);
    float* part = (float*)((char*)d_ws + (1 << 20));

    hipMemsetAsync(d_ws, 0, 516, stream);
    k_wpack<<<64, 256, 0, stream>>>(gw, wp);
    k_gemm<<<NKQ * (NTOK / TPB), 256, 0, stream>>>(x, wp, part);
    k_reduce<<<NTOK / 16, 256, 0, stream>>>(part, out, wsf, wsf + 64, wsf + 128);
    k_final<<<1, 64, 0, stream>>>(wsf, out);
}